// Round 1
// baseline (23106.677 us; speedup 1.0000x reference)
//
#include <hip/hip_runtime.h>
#include <hip/hip_bf16.h>

#define N_NODES 50000
#define N_EDGES 800000
#define MAX_ITER 20

__device__ __forceinline__ float gelu_f(float x){
  return 0.5f*x*(1.0f+erff(x*0.70710678118654752f));
}

// ---------------- setup: degree + counts ----------------
__global__ void deg_cnt_kernel(const int* __restrict__ col, const float* __restrict__ attr,
                               float* __restrict__ deg, int* __restrict__ cnt){
  int e = blockIdx.x*256 + threadIdx.x;
  if (e < N_EDGES){
    int c = col[e];
    atomicAdd(&deg[c], attr[e]);
    atomicAdd(&cnt[c], 1);
  }
}

__global__ void norm_kernel(const int* __restrict__ row, const int* __restrict__ col,
                            const float* __restrict__ attr, const float* __restrict__ deg,
                            float* __restrict__ nrm){
  int e = blockIdx.x*256 + threadIdx.x;
  if (e < N_EDGES){
    float dr = deg[row[e]], dc = deg[col[e]];
    float ir = dr > 0.f ? rsqrtf(dr) : 0.f;
    float ic = dc > 0.f ? rsqrtf(dc) : 0.f;
    nrm[e] = ir * attr[e] * ic;
  }
}

// single-block exclusive scan of cnt -> starts (N_NODES+1), also copies to cursor
__global__ void scan_kernel(const int* __restrict__ cnt, int* __restrict__ starts,
                            int* __restrict__ cursor){
  __shared__ int buf[1024];
  __shared__ int carry;
  int tid = threadIdx.x;
  if (tid==0) carry = 0;
  __syncthreads();
  for (int base=0; base<N_NODES; base+=1024){
    int i = base+tid;
    int v = (i<N_NODES)? cnt[i] : 0;
    int cv = carry;
    buf[tid]=v;
    __syncthreads();
    for (int off=1; off<1024; off<<=1){
      int t = (tid>=off)? buf[tid-off] : 0;
      __syncthreads();
      buf[tid]+=t;
      __syncthreads();
    }
    int excl = buf[tid]-v+cv;
    if (i<N_NODES){ starts[i]=excl; cursor[i]=excl; }
    __syncthreads();
    if (tid==0) carry = cv + buf[1023];
    __syncthreads();
  }
  if (tid==0) starts[N_NODES] = carry;
}

__global__ void fill_kernel(const int* __restrict__ row, const int* __restrict__ col,
                            const float* __restrict__ nrm, int* __restrict__ cursor,
                            int* __restrict__ csr_row, float* __restrict__ csr_nrm){
  int e = blockIdx.x*256+threadIdx.x;
  if (e<N_EDGES){
    int c = col[e];
    int p = atomicAdd(&cursor[c],1);
    csr_row[p]=row[e];
    csr_nrm[p]=nrm[e];
  }
}

// ---------------- up MLP: z0 = gelu(x@W1+b1)@W2+b2 ----------------
__global__ __launch_bounds__(256) void mlp_up_kernel(
    const float* __restrict__ x, const float* __restrict__ w1, const float* __restrict__ b1,
    const float* __restrict__ w2, const float* __restrict__ b2, float* __restrict__ z){
  __shared__ float sw1[4*64];
  __shared__ float sw2[64*64];
  __shared__ float sb1[64], sb2[64];
  __shared__ float t1s[4][64];
  int tid = threadIdx.x;
  for (int i=tid;i<256;i+=256) sw1[i]=w1[i];
  for (int i=tid;i<4096;i+=256) sw2[i]=w2[i];
  if (tid<64){ sb1[tid]=b1[tid]; sb2[tid]=b2[tid]; }
  __syncthreads();
  int g = tid>>6;              // node group 0..3
  int c = tid&63;
  int node = blockIdx.x*4 + g;
  float acc = sb1[c];
  #pragma unroll
  for (int k=0;k<4;k++) acc += x[node*4+k]*sw1[k*64+c];
  t1s[g][c] = gelu_f(acc);
  __syncthreads();
  float acc2 = sb2[c];
  #pragma unroll 8
  for (int k=0;k<64;k++) acc2 += t1s[g][k]*sw2[k*64+c];
  z[(size_t)node*64+c] = acc2;
}

// ---------------- concat [z | pos] -> h0 (width 67) ----------------
__global__ void concat_kernel(const float* __restrict__ z, const float* __restrict__ pos,
                              float* __restrict__ h0){
  int i = blockIdx.x*256+threadIdx.x;
  if (i < N_NODES*67){
    int v = i/67, f = i - v*67;
    h0[i] = (f<64)? z[(size_t)v*64+f] : pos[(size_t)v*3 + (f-64)];
  }
}

// ---------------- CSR pull propagate: out[v] = sum_in h[row_e]*nrm_e ----------------
template<int W>
__global__ __launch_bounds__(128) void prop_kernel(
    const float* __restrict__ h, float* __restrict__ out,
    const int* __restrict__ starts, const int* __restrict__ csr_row,
    const float* __restrict__ csr_nrm){
  int v = blockIdx.x;
  int f = threadIdx.x;
  int s = starts[v], e = starts[v+1];
  if (f >= W) return;
  float acc = 0.f;
  for (int i=s;i<e;++i){
    int r = csr_row[i];
    float nm = csr_nrm[i];
    acc = fmaf(h[(size_t)r*W+f], nm, acc);
  }
  out[(size_t)v*W+f]=acc;
}

// ---------------- fused 4-matrix TAG gemm: out = b + sum_j Hj @ W[j] (+relu) ----------------
template<int KC, int OUTC, bool RELU>
__global__ __launch_bounds__(256) void tag_gemm(
    const float* __restrict__ H0, const float* __restrict__ H1,
    const float* __restrict__ H2, const float* __restrict__ H3,
    const float* __restrict__ Wst, const float* __restrict__ bias,
    float* __restrict__ out){
  constexpr int CG  = OUTC/4;      // colgroups of 4
  constexpr int TY  = 256/CG;
  constexpr int NPT = 2;
  constexpr int NPB = TY*NPT;      // nodes per block
  constexpr int KCH = 16;
  __shared__ float sW[4][KCH][OUTC];
  int tx = threadIdx.x % CG;
  int ty = threadIdx.x / CG;
  int n0 = blockIdx.x*NPB + ty*NPT;
  int nd0 = min(n0,   N_NODES-1);
  int nd1 = min(n0+1, N_NODES-1);
  const float* Hs[4] = {H0,H1,H2,H3};
  float acc[NPT][4];
  #pragma unroll
  for (int p=0;p<NPT;p++){ acc[p][0]=0;acc[p][1]=0;acc[p][2]=0;acc[p][3]=0; }
  for (int kb=0; kb<KC; kb+=KCH){
    __syncthreads();
    constexpr int NF4 = 4*KCH*OUTC/4;
    for (int f4=threadIdx.x; f4<NF4; f4+=256){
      int j  = f4 / (KCH*OUTC/4);
      int r  = f4 % (KCH*OUTC/4);
      int kk = r / (OUTC/4);
      int c4 = r % (OUTC/4);
      float4 val = make_float4(0.f,0.f,0.f,0.f);
      if (kb+kk < KC) val = *(const float4*)(Wst + ((size_t)j*KC + kb+kk)*OUTC + c4*4);
      *(float4*)&sW[j][kk][c4*4] = val;
    }
    __syncthreads();
    int kn = min(KCH, KC-kb);
    if (kn == KCH){
      #pragma unroll
      for (int kk=0; kk<KCH; ++kk){
        int k = kb+kk;
        #pragma unroll
        for (int j=0;j<4;j++){
          float4 w4 = *(const float4*)&sW[j][kk][tx*4];
          float hv0 = Hs[j][(size_t)nd0*KC + k];
          float hv1 = Hs[j][(size_t)nd1*KC + k];
          acc[0][0] = fmaf(hv0,w4.x,acc[0][0]); acc[0][1] = fmaf(hv0,w4.y,acc[0][1]);
          acc[0][2] = fmaf(hv0,w4.z,acc[0][2]); acc[0][3] = fmaf(hv0,w4.w,acc[0][3]);
          acc[1][0] = fmaf(hv1,w4.x,acc[1][0]); acc[1][1] = fmaf(hv1,w4.y,acc[1][1]);
          acc[1][2] = fmaf(hv1,w4.z,acc[1][2]); acc[1][3] = fmaf(hv1,w4.w,acc[1][3]);
        }
      }
    } else {
      for (int kk=0; kk<kn; ++kk){
        int k = kb+kk;
        #pragma unroll
        for (int j=0;j<4;j++){
          float4 w4 = *(const float4*)&sW[j][kk][tx*4];
          float hv0 = Hs[j][(size_t)nd0*KC + k];
          float hv1 = Hs[j][(size_t)nd1*KC + k];
          acc[0][0] = fmaf(hv0,w4.x,acc[0][0]); acc[0][1] = fmaf(hv0,w4.y,acc[0][1]);
          acc[0][2] = fmaf(hv0,w4.z,acc[0][2]); acc[0][3] = fmaf(hv0,w4.w,acc[0][3]);
          acc[1][0] = fmaf(hv1,w4.x,acc[1][0]); acc[1][1] = fmaf(hv1,w4.y,acc[1][1]);
          acc[1][2] = fmaf(hv1,w4.z,acc[1][2]); acc[1][3] = fmaf(hv1,w4.w,acc[1][3]);
        }
      }
    }
  }
  #pragma unroll
  for (int p=0;p<NPT;p++){
    int node = n0+p;
    if (node < N_NODES){
      #pragma unroll
      for (int q=0;q<4;q++){
        float v = acc[p][q] + bias[tx*4+q];
        if (RELU) v = fmaxf(v, 0.f);
        out[(size_t)node*OUTC + tx*4 + q] = v;
      }
    }
  }
}

// ---------------- log_softmax over 64 cols (wave per node) ----------------
__global__ __launch_bounds__(256) void logsm_kernel(const float* __restrict__ h, float* __restrict__ out){
  int node = blockIdx.x*4 + (threadIdx.x>>6);
  int c = threadIdx.x & 63;
  float v = h[(size_t)node*64+c];
  float m = v;
  #pragma unroll
  for (int off=32; off; off>>=1) m = fmaxf(m, __shfl_xor(m, off, 64));
  float ex = expf(v-m);
  float s = ex;
  #pragma unroll
  for (int off=32; off; off>>=1) s += __shfl_xor(s, off, 64);
  out[(size_t)node*64+c] = v - m - logf(s);
}

// ---------------- down MLP: out = gelu(z@dw1+db1)*dw2+db2 ----------------
__global__ __launch_bounds__(256) void mlp_down_kernel(
    const float* __restrict__ zs, const float* __restrict__ dw1, const float* __restrict__ db1,
    const float* __restrict__ dw2, const float* __restrict__ db2, float* __restrict__ out){
  int node = blockIdx.x*4 + (threadIdx.x>>6);
  int c = threadIdx.x & 63;
  float v = zs[(size_t)node*64+c]*dw1[c];
  #pragma unroll
  for (int off=32; off; off>>=1) v += __shfl_xor(v, off, 64);
  if (c==0) out[node] = gelu_f(v + db1[0]) * dw2[0] + db2[0];
}

extern "C" void kernel_launch(void* const* d_in, const int* in_sizes, int n_in,
                              void* d_out, int out_size, void* d_ws, size_t ws_size,
                              hipStream_t stream){
  const float* x     = (const float*)d_in[0];
  const float* pos   = (const float*)d_in[1];
  const float* eattr = (const float*)d_in[2];
  const float* up_w1 = (const float*)d_in[3];
  const float* up_b1 = (const float*)d_in[4];
  const float* up_w2 = (const float*)d_in[5];
  const float* up_b2 = (const float*)d_in[6];
  const float* c1_w  = (const float*)d_in[7];
  const float* c1_b  = (const float*)d_in[8];
  const float* c2_w  = (const float*)d_in[9];
  const float* c2_b  = (const float*)d_in[10];
  const float* c3_w  = (const float*)d_in[11];
  const float* c3_b  = (const float*)d_in[12];
  const float* dw1   = (const float*)d_in[13];
  const float* db1   = (const float*)d_in[14];
  const float* dw2   = (const float*)d_in[15];
  const float* db2   = (const float*)d_in[16];
  const int*   eidx  = (const int*)d_in[17];
  const int* row = eidx;
  const int* col = eidx + N_EDGES;

  char* wsp = (char*)d_ws;
  size_t off = 0;
  auto alloc = [&](size_t bytes)->char*{
    char* p = wsp + off;
    off = (off + bytes + 255) & ~(size_t)255;
    return p;
  };
  float* deg    = (float*)alloc((size_t)N_NODES*4);
  int*   cnt    = (int*)  alloc((size_t)N_NODES*4);
  int*   starts = (int*)  alloc((size_t)(N_NODES+1)*4);
  int*   cursor = (int*)  alloc((size_t)N_NODES*4);
  float* nrm    = (float*)alloc((size_t)N_EDGES*4);
  int*   crow   = (int*)  alloc((size_t)N_EDGES*4);
  float* cnrm   = (float*)alloc((size_t)N_EDGES*4);
  float* zA     = (float*)alloc((size_t)N_NODES*64*4);
  float* zB     = (float*)alloc((size_t)N_NODES*64*4);
  float* h0     = (float*)alloc((size_t)N_NODES*67*4);
  float* t1     = (float*)alloc((size_t)N_NODES*128*4);
  float* t2     = (float*)alloc((size_t)N_NODES*128*4);
  float* t3     = (float*)alloc((size_t)N_NODES*64*4);
  float* p1     = (float*)alloc((size_t)N_NODES*128*4);
  float* p2     = (float*)alloc((size_t)N_NODES*128*4);
  float* p3     = (float*)alloc((size_t)N_NODES*128*4);

  float* outv  = (float*)d_out;            // (N,1)
  float* zstar = (float*)d_out + N_NODES;  // (N,64)

  hipMemsetAsync(deg, 0, (size_t)N_NODES*4, stream);
  hipMemsetAsync(cnt, 0, (size_t)N_NODES*4, stream);
  int eb = (N_EDGES+255)/256;
  deg_cnt_kernel<<<eb,256,0,stream>>>(col, eattr, deg, cnt);
  norm_kernel<<<eb,256,0,stream>>>(row, col, eattr, deg, nrm);
  scan_kernel<<<1,1024,0,stream>>>(cnt, starts, cursor);
  fill_kernel<<<eb,256,0,stream>>>(row, col, nrm, cursor, crow, cnrm);
  mlp_up_kernel<<<N_NODES/4,256,0,stream>>>(x, up_w1, up_b1, up_w2, up_b2, zA);

  const int g128 = (N_NODES+15)/16;   // tag_gemm OUTC=128: 16 nodes/block
  const int g64  = (N_NODES+31)/32;   // tag_gemm OUTC=64:  32 nodes/block

  float* zin = zA;
  for (int it=0; it<=MAX_ITER; ++it){
    float* zout = (it==MAX_ITER)? zstar : ((zin==zA)? zB : zA);
    concat_kernel<<<(N_NODES*67+255)/256,256,0,stream>>>(zin, pos, h0);

    prop_kernel<67><<<N_NODES,128,0,stream>>>(h0,p1,starts,crow,cnrm);
    prop_kernel<67><<<N_NODES,128,0,stream>>>(p1,p2,starts,crow,cnrm);
    prop_kernel<67><<<N_NODES,128,0,stream>>>(p2,p3,starts,crow,cnrm);
    tag_gemm<67,128,true><<<g128,256,0,stream>>>(h0,p1,p2,p3,c1_w,c1_b,t1);

    prop_kernel<128><<<N_NODES,128,0,stream>>>(t1,p1,starts,crow,cnrm);
    prop_kernel<128><<<N_NODES,128,0,stream>>>(p1,p2,starts,crow,cnrm);
    prop_kernel<128><<<N_NODES,128,0,stream>>>(p2,p3,starts,crow,cnrm);
    tag_gemm<128,128,true><<<g128,256,0,stream>>>(t1,p1,p2,p3,c2_w,c2_b,t2);

    prop_kernel<128><<<N_NODES,128,0,stream>>>(t2,p1,starts,crow,cnrm);
    prop_kernel<128><<<N_NODES,128,0,stream>>>(p1,p2,starts,crow,cnrm);
    prop_kernel<128><<<N_NODES,128,0,stream>>>(p2,p3,starts,crow,cnrm);
    tag_gemm<128,64,false><<<g64,256,0,stream>>>(t2,p1,p2,p3,c3_w,c3_b,t3);

    logsm_kernel<<<N_NODES/4,256,0,stream>>>(t3, zout);
    zin = zout;
  }
  mlp_down_kernel<<<N_NODES/4,256,0,stream>>>(zstar, dw1, db1, dw2, db2, outv);
}

// Round 2
// 12730.031 us; speedup vs baseline: 1.8151x; 1.8151x over previous
//
#include <hip/hip_runtime.h>
#include <hip/hip_bf16.h>

#define N_NODES 50000
#define N_EDGES 800000
#define MAX_ITER 20

typedef __attribute__((ext_vector_type(8))) short bf16x8;
typedef __attribute__((ext_vector_type(4))) float f32x4;

__device__ __forceinline__ float gelu_f(float x){
  return 0.5f*x*(1.0f+erff(x*0.70710678118654752f));
}
__device__ __forceinline__ float b2f(ushort u){ return __uint_as_float(((uint)u)<<16); }
__device__ __forceinline__ ushort f2b(float f){
  uint x = __float_as_uint(f);
  uint r = (x + 0x7fffu + ((x>>16)&1u)) >> 16;
  return (ushort)r;
}

// ---------------- setup: degree + counts ----------------
__global__ void deg_cnt_kernel(const int* __restrict__ col, const float* __restrict__ attr,
                               float* __restrict__ deg, int* __restrict__ cnt){
  int e = blockIdx.x*256 + threadIdx.x;
  if (e < N_EDGES){
    int c = col[e];
    atomicAdd(&deg[c], attr[e]);
    atomicAdd(&cnt[c], 1);
  }
}

__global__ void norm_kernel(const int* __restrict__ row, const int* __restrict__ col,
                            const float* __restrict__ attr, const float* __restrict__ deg,
                            float* __restrict__ nrm){
  int e = blockIdx.x*256 + threadIdx.x;
  if (e < N_EDGES){
    float dr = deg[row[e]], dc = deg[col[e]];
    float ir = dr > 0.f ? rsqrtf(dr) : 0.f;
    float ic = dc > 0.f ? rsqrtf(dc) : 0.f;
    nrm[e] = ir * attr[e] * ic;
  }
}

// single-block exclusive scan of cnt -> starts (N_NODES+1), also copies to cursor
__global__ void scan_kernel(const int* __restrict__ cnt, int* __restrict__ starts,
                            int* __restrict__ cursor){
  __shared__ int buf[1024];
  __shared__ int carry;
  int tid = threadIdx.x;
  if (tid==0) carry = 0;
  __syncthreads();
  for (int base=0; base<N_NODES; base+=1024){
    int i = base+tid;
    int v = (i<N_NODES)? cnt[i] : 0;
    int cv = carry;
    buf[tid]=v;
    __syncthreads();
    for (int off=1; off<1024; off<<=1){
      int t = (tid>=off)? buf[tid-off] : 0;
      __syncthreads();
      buf[tid]+=t;
      __syncthreads();
    }
    int excl = buf[tid]-v+cv;
    if (i<N_NODES){ starts[i]=excl; cursor[i]=excl; }
    __syncthreads();
    if (tid==0) carry = cv + buf[1023];
    __syncthreads();
  }
  if (tid==0) starts[N_NODES] = carry;
}

__global__ void fill_kernel(const int* __restrict__ row, const int* __restrict__ col,
                            const float* __restrict__ nrm, int* __restrict__ cursor,
                            int* __restrict__ csr_row, float* __restrict__ csr_nrm){
  int e = blockIdx.x*256+threadIdx.x;
  if (e<N_EDGES){
    int c = col[e];
    int p = atomicAdd(&cursor[c],1);
    csr_row[p]=row[e];
    csr_nrm[p]=nrm[e];
  }
}

// ---------------- pack TAG weights [4][KC][OUTC] fp32 -> bf16 frag layout, K padded to 128 ----------------
template<int KC, int OUTC>
__global__ __launch_bounds__(256) void pack_w(const float* __restrict__ W, ushort* __restrict__ PB){
  int i = blockIdx.x*256+threadIdx.x;   // i = ((j*16+kb)*OUTC + n)*8 + e
  if (i < 4*16*OUTC*8){
    int e  = i & 7;
    int n  = (i>>3) % OUTC;
    int kb = ((i>>3)/OUTC) % 16;
    int j  = i/(8*OUTC*16);
    int k  = kb*8+e;
    float val = (k<KC)? W[((size_t)j*KC+k)*OUTC + n] : 0.f;
    PB[i] = f2b(val);
  }
}

// ---------------- up MLP: z0 = gelu(x@W1+b1)@W2+b2 -> h0[:, :64] bf16 ----------------
__global__ __launch_bounds__(256) void mlp_up_kernel(
    const float* __restrict__ x, const float* __restrict__ w1, const float* __restrict__ b1,
    const float* __restrict__ w2, const float* __restrict__ b2, ushort* __restrict__ h0){
  __shared__ float sw1[4*64];
  __shared__ float sw2[64*64];
  __shared__ float sb1[64], sb2[64];
  __shared__ float t1s[4][64];
  int tid = threadIdx.x;
  for (int i=tid;i<256;i+=256) sw1[i]=w1[i];
  for (int i=tid;i<4096;i+=256) sw2[i]=w2[i];
  if (tid<64){ sb1[tid]=b1[tid]; sb2[tid]=b2[tid]; }
  __syncthreads();
  int g = tid>>6;
  int c = tid&63;
  int node = blockIdx.x*4 + g;
  float acc = sb1[c];
  #pragma unroll
  for (int k=0;k<4;k++) acc += x[node*4+k]*sw1[k*64+c];
  t1s[g][c] = gelu_f(acc);
  __syncthreads();
  float acc2 = sb2[c];
  #pragma unroll 8
  for (int k=0;k<64;k++) acc2 += t1s[g][k]*sw2[k*64+c];
  h0[(size_t)node*128+c] = f2b(acc2);
}

// ---------------- h0 tail init: pos (bf16) + zero pads ----------------
__global__ __launch_bounds__(256) void h0_init_kernel(const float* __restrict__ pos, ushort* __restrict__ h0){
  int i = blockIdx.x*256+threadIdx.x;   // over N_NODES*64
  int v = i>>6, c = i&63;
  if (v < N_NODES){
    float val = (c<3)? pos[(size_t)v*3+c] : 0.f;
    h0[(size_t)v*128 + 64 + c] = f2b(val);
  }
}

// ---------------- CSR pull propagate (bf16, stride 128): wave per node ----------------
__global__ __launch_bounds__(256) void prop_bf16(
    const ushort* __restrict__ h, ushort* __restrict__ out,
    const int* __restrict__ starts, const int* __restrict__ crow,
    const float* __restrict__ cnrm){
  int wv = threadIdx.x >> 6;
  int v = blockIdx.x*4 + wv;
  int t = threadIdx.x & 63;
  int s = starts[v], e = starts[v+1];
  float a0=0.f, a1=0.f;
  for (int i=s; i<e; i+=64){
    int cnt = e - i; if (cnt > 64) cnt = 64;
    int r = 0; float nm = 0.f;
    if (t < cnt){ r = crow[i+t]; nm = cnrm[i+t]; }
    for (int j=0; j<cnt; ++j){
      int rr = __shfl(r, j, 64);
      float nmj = __shfl(nm, j, 64);
      uint hv = *(const uint*)(h + (size_t)rr*128 + 2*t);
      a0 = fmaf(__uint_as_float(hv<<16),         nmj, a0);
      a1 = fmaf(__uint_as_float(hv & 0xffff0000u), nmj, a1);
    }
  }
  uint p = (uint)f2b(a0) | ((uint)f2b(a1)<<16);
  *(uint*)(out + (size_t)v*128 + 2*t) = p;
}

// ---------------- MFMA TAG gemm: out = act(bias + sum_j Hj @ Wj) ----------------
// ACT: 1=relu->bf16(stride128), 2=logsoftmax->bf16 h0 z-part(stride128), 3=logsoftmax->fp32 zstar(stride64)
template<int OUTC, int ACT>
__global__ __launch_bounds__(256) void tag_gemm_mfma(
    const ushort* __restrict__ H0, const ushort* __restrict__ H1,
    const ushort* __restrict__ H2, const ushort* __restrict__ H3,
    const ushort* __restrict__ PB, const float* __restrict__ bias,
    void* __restrict__ outp){
  constexpr int NT = OUTC/16;
  int lane = threadIdx.x & 63;
  int wv   = threadIdx.x >> 6;
  int m0 = blockIdx.x*64 + wv*16;
  int lr = lane & 15, lg = lane >> 4;
  int arow = m0 + lr; if (arow > N_NODES-1) arow = N_NODES-1;
  const ushort* Hs[4] = {H0,H1,H2,H3};
  f32x4 acc[NT];
  #pragma unroll
  for (int t=0;t<NT;t++) acc[t] = (f32x4){0.f,0.f,0.f,0.f};
  #pragma unroll
  for (int j=0;j<4;j++){
    const ushort* Hj  = Hs[j] + (size_t)arow*128 + lg*8;
    const ushort* PBj = PB + (size_t)j*16*OUTC*8;
    #pragma unroll
    for (int ks=0; ks<4; ks++){
      bf16x8 af = *(const bf16x8*)(Hj + ks*32);
      int kb = ks*4 + lg;
      #pragma unroll
      for (int t=0;t<NT;t++){
        bf16x8 bf = *(const bf16x8*)(PBj + ((size_t)kb*OUTC + t*16 + lr)*8);
        acc[t] = __builtin_amdgcn_mfma_f32_16x16x32_bf16(af, bf, acc[t], 0, 0, 0);
      }
    }
  }
  if (ACT == 1){
    ushort* out = (ushort*)outp;
    #pragma unroll
    for (int t=0;t<NT;t++){
      float b = bias[t*16+lr];
      #pragma unroll
      for (int q=0;q<4;q++){
        int node = m0 + lg*4 + q;
        if (node < N_NODES){
          float v = acc[t][q] + b;
          v = fmaxf(v, 0.f);
          out[(size_t)node*128 + t*16 + lr] = f2b(v);
        }
      }
    }
  } else {
    float vv[NT][4];
    #pragma unroll
    for (int t=0;t<NT;t++){
      float b = bias[t*16+lr];
      #pragma unroll
      for (int q=0;q<4;q++) vv[t][q] = acc[t][q] + b;
    }
    #pragma unroll
    for (int q=0;q<4;q++){
      float m = vv[0][q];
      #pragma unroll
      for (int t=1;t<NT;t++) m = fmaxf(m, vv[t][q]);
      #pragma unroll
      for (int off=1; off<16; off<<=1) m = fmaxf(m, __shfl_xor(m, off, 64));
      float s = 0.f;
      #pragma unroll
      for (int t=0;t<NT;t++) s += __expf(vv[t][q]-m);
      #pragma unroll
      for (int off=1; off<16; off<<=1) s += __shfl_xor(s, off, 64);
      float lse = m + __logf(s);
      int node = m0 + lg*4 + q;
      if (node < N_NODES){
        if (ACT == 2){
          ushort* h0z = (ushort*)outp;
          #pragma unroll
          for (int t=0;t<NT;t++) h0z[(size_t)node*128 + t*16 + lr] = f2b(vv[t][q]-lse);
        } else {
          float* zs = (float*)outp;
          #pragma unroll
          for (int t=0;t<NT;t++) zs[(size_t)node*64 + t*16 + lr] = vv[t][q]-lse;
        }
      }
    }
  }
}

// ---------------- down MLP: out = gelu(z@dw1+db1)*dw2+db2 ----------------
__global__ __launch_bounds__(256) void mlp_down_kernel(
    const float* __restrict__ zs, const float* __restrict__ dw1, const float* __restrict__ db1,
    const float* __restrict__ dw2, const float* __restrict__ db2, float* __restrict__ out){
  int node = blockIdx.x*4 + (threadIdx.x>>6);
  int c = threadIdx.x & 63;
  float v = zs[(size_t)node*64+c]*dw1[c];
  #pragma unroll
  for (int off=32; off; off>>=1) v += __shfl_xor(v, off, 64);
  if (c==0) out[node] = gelu_f(v + db1[0]) * dw2[0] + db2[0];
}

extern "C" void kernel_launch(void* const* d_in, const int* in_sizes, int n_in,
                              void* d_out, int out_size, void* d_ws, size_t ws_size,
                              hipStream_t stream){
  const float* x     = (const float*)d_in[0];
  const float* pos   = (const float*)d_in[1];
  const float* eattr = (const float*)d_in[2];
  const float* up_w1 = (const float*)d_in[3];
  const float* up_b1 = (const float*)d_in[4];
  const float* up_w2 = (const float*)d_in[5];
  const float* up_b2 = (const float*)d_in[6];
  const float* c1_w  = (const float*)d_in[7];
  const float* c1_b  = (const float*)d_in[8];
  const float* c2_w  = (const float*)d_in[9];
  const float* c2_b  = (const float*)d_in[10];
  const float* c3_w  = (const float*)d_in[11];
  const float* c3_b  = (const float*)d_in[12];
  const float* dw1   = (const float*)d_in[13];
  const float* db1   = (const float*)d_in[14];
  const float* dw2   = (const float*)d_in[15];
  const float* db2   = (const float*)d_in[16];
  const int*   eidx  = (const int*)d_in[17];
  const int* row = eidx;
  const int* col = eidx + N_EDGES;

  char* wsp = (char*)d_ws;
  size_t off = 0;
  auto alloc = [&](size_t bytes)->char*{
    char* p = wsp + off;
    off = (off + bytes + 255) & ~(size_t)255;
    return p;
  };
  float*  deg    = (float*)alloc((size_t)N_NODES*4);
  int*    cnt    = (int*)  alloc((size_t)N_NODES*4);
  int*    starts = (int*)  alloc((size_t)(N_NODES+1)*4);
  int*    cursor = (int*)  alloc((size_t)N_NODES*4);
  float*  nrm    = (float*)alloc((size_t)N_EDGES*4);
  int*    crow   = (int*)  alloc((size_t)N_EDGES*4);
  float*  cnrm   = (float*)alloc((size_t)N_EDGES*4);
  ushort* h0     = (ushort*)alloc((size_t)N_NODES*128*2);
  ushort* t1     = (ushort*)alloc((size_t)N_NODES*128*2);
  ushort* t2     = (ushort*)alloc((size_t)N_NODES*128*2);
  ushort* p1     = (ushort*)alloc((size_t)N_NODES*128*2);
  ushort* p2     = (ushort*)alloc((size_t)N_NODES*128*2);
  ushort* p3     = (ushort*)alloc((size_t)N_NODES*128*2);
  ushort* PB1    = (ushort*)alloc((size_t)4*16*128*8*2);
  ushort* PB2    = (ushort*)alloc((size_t)4*16*128*8*2);
  ushort* PB3    = (ushort*)alloc((size_t)4*16*64*8*2);

  float* outv  = (float*)d_out;            // (N,1)
  float* zstar = (float*)d_out + N_NODES;  // (N,64)

  hipMemsetAsync(deg, 0, (size_t)N_NODES*4, stream);
  hipMemsetAsync(cnt, 0, (size_t)N_NODES*4, stream);
  int eb = (N_EDGES+255)/256;
  deg_cnt_kernel<<<eb,256,0,stream>>>(col, eattr, deg, cnt);
  norm_kernel<<<eb,256,0,stream>>>(row, col, eattr, deg, nrm);
  scan_kernel<<<1,1024,0,stream>>>(cnt, starts, cursor);
  fill_kernel<<<eb,256,0,stream>>>(row, col, nrm, cursor, crow, cnrm);
  pack_w<67,128><<<256,256,0,stream>>>(c1_w, PB1);
  pack_w<128,128><<<256,256,0,stream>>>(c2_w, PB2);
  pack_w<128,64><<<128,256,0,stream>>>(c3_w, PB3);
  mlp_up_kernel<<<N_NODES/4,256,0,stream>>>(x, up_w1, up_b1, up_w2, up_b2, h0);
  h0_init_kernel<<<(N_NODES*64)/256,256,0,stream>>>(pos, h0);

  const int gprop = N_NODES/4;             // 12500 blocks, 4 nodes/block
  const int ggemm = (N_NODES+63)/64;       // 782 blocks

  for (int it=0; it<=MAX_ITER; ++it){
    prop_bf16<<<gprop,256,0,stream>>>(h0,p1,starts,crow,cnrm);
    prop_bf16<<<gprop,256,0,stream>>>(p1,p2,starts,crow,cnrm);
    prop_bf16<<<gprop,256,0,stream>>>(p2,p3,starts,crow,cnrm);
    tag_gemm_mfma<128,1><<<ggemm,256,0,stream>>>(h0,p1,p2,p3,PB1,c1_b,t1);

    prop_bf16<<<gprop,256,0,stream>>>(t1,p1,starts,crow,cnrm);
    prop_bf16<<<gprop,256,0,stream>>>(p1,p2,starts,crow,cnrm);
    prop_bf16<<<gprop,256,0,stream>>>(p2,p3,starts,crow,cnrm);
    tag_gemm_mfma<128,1><<<ggemm,256,0,stream>>>(t1,p1,p2,p3,PB2,c2_b,t2);

    prop_bf16<<<gprop,256,0,stream>>>(t2,p1,starts,crow,cnrm);
    prop_bf16<<<gprop,256,0,stream>>>(p1,p2,starts,crow,cnrm);
    prop_bf16<<<gprop,256,0,stream>>>(p2,p3,starts,crow,cnrm);
    if (it < MAX_ITER){
      tag_gemm_mfma<64,2><<<ggemm,256,0,stream>>>(t2,p1,p2,p3,PB3,c3_b,h0);
    } else {
      tag_gemm_mfma<64,3><<<ggemm,256,0,stream>>>(t2,p1,p2,p3,PB3,c3_b,zstar);
    }
  }
  mlp_down_kernel<<<N_NODES/4,256,0,stream>>>(zstar, dw1, db1, dw2, db2, outv);
}

// Round 3
// 7226.514 us; speedup vs baseline: 3.1975x; 1.7616x over previous
//
#include <hip/hip_runtime.h>
#include <hip/hip_bf16.h>

#define N_NODES 50000
#define N_EDGES 800000
#define MAX_ITER 20

typedef __attribute__((ext_vector_type(8))) short bf16x8;
typedef __attribute__((ext_vector_type(4))) float f32x4;

__device__ __forceinline__ float gelu_f(float x){
  return 0.5f*x*(1.0f+erff(x*0.70710678118654752f));
}
__device__ __forceinline__ ushort f2b(float f){
  uint x = __float_as_uint(f);
  uint r = (x + 0x7fffu + ((x>>16)&1u)) >> 16;
  return (ushort)r;
}

// ---------------- setup: degree + counts ----------------
__global__ void deg_cnt_kernel(const int* __restrict__ col, const float* __restrict__ attr,
                               float* __restrict__ deg, int* __restrict__ cnt){
  int e = blockIdx.x*256 + threadIdx.x;
  if (e < N_EDGES){
    int c = col[e];
    atomicAdd(&deg[c], attr[e]);
    atomicAdd(&cnt[c], 1);
  }
}

__global__ void norm_kernel(const int* __restrict__ row, const int* __restrict__ col,
                            const float* __restrict__ attr, const float* __restrict__ deg,
                            float* __restrict__ nrm){
  int e = blockIdx.x*256 + threadIdx.x;
  if (e < N_EDGES){
    float dr = deg[row[e]], dc = deg[col[e]];
    float ir = dr > 0.f ? rsqrtf(dr) : 0.f;
    float ic = dc > 0.f ? rsqrtf(dc) : 0.f;
    nrm[e] = ir * attr[e] * ic;
  }
}

__global__ void scan_kernel(const int* __restrict__ cnt, int* __restrict__ starts,
                            int* __restrict__ cursor){
  __shared__ int buf[1024];
  __shared__ int carry;
  int tid = threadIdx.x;
  if (tid==0) carry = 0;
  __syncthreads();
  for (int base=0; base<N_NODES; base+=1024){
    int i = base+tid;
    int v = (i<N_NODES)? cnt[i] : 0;
    int cv = carry;
    buf[tid]=v;
    __syncthreads();
    for (int off=1; off<1024; off<<=1){
      int t = (tid>=off)? buf[tid-off] : 0;
      __syncthreads();
      buf[tid]+=t;
      __syncthreads();
    }
    int excl = buf[tid]-v+cv;
    if (i<N_NODES){ starts[i]=excl; cursor[i]=excl; }
    __syncthreads();
    if (tid==0) carry = cv + buf[1023];
    __syncthreads();
  }
  if (tid==0) starts[N_NODES] = carry;
}

__global__ void fill_kernel(const int* __restrict__ row, const int* __restrict__ col,
                            const float* __restrict__ nrm, int* __restrict__ cursor,
                            int* __restrict__ csr_row, float* __restrict__ csr_nrm){
  int e = blockIdx.x*256+threadIdx.x;
  if (e<N_EDGES){
    int c = col[e];
    int p = atomicAdd(&cursor[c],1);
    csr_row[p]=row[e];
    csr_nrm[p]=nrm[e];
  }
}

// ---------------- weight packs (bf16 MFMA fragment layout) ----------------
// PB[((j*KB + kb)*OUTC + n)*8 + e], k = kb*8+e
__global__ void pack_w1(const float* __restrict__ W, ushort* __restrict__ PB){
  // c1_w [4][67][128], z-part rows 0..63 -> KB=8, OUTC=128
  int i = blockIdx.x*256+threadIdx.x;
  if (i < 4*8*128*8){
    int e = i&7; int n = (i>>3)&127; int kb = (i>>10)&7; int j = i>>13;
    int k = kb*8+e;
    PB[i] = f2b(W[((size_t)j*67 + k)*128 + n]);
  }
}
__global__ void pack_w2(const float* __restrict__ W, ushort* __restrict__ PB){
  // c2_w [4][128][128] -> KB=16, OUTC=128
  int i = blockIdx.x*256+threadIdx.x;
  if (i < 4*16*128*8){
    int e = i&7; int n = (i>>3)&127; int kb = (i>>10)&15; int j = i>>14;
    int k = kb*8+e;
    PB[i] = f2b(W[((size_t)j*128 + k)*128 + n]);
  }
}
__global__ void pack_w3(const float* __restrict__ W, ushort* __restrict__ PB){
  // c3_w [4][128][64] -> single K=128, OUT=256 (col n: j=n>>6, c=n&63); KB=16
  int i = blockIdx.x*256+threadIdx.x;
  if (i < 16*256*8){
    int e = i&7; int n = (i>>3)&255; int kb = i>>11;
    int k = kb*8+e;
    PB[i] = f2b(W[(((size_t)(n>>6))*128 + k)*64 + (n&63)]);
  }
}

// ---------------- up MLP -> z (bf16, stride 64) ----------------
__global__ __launch_bounds__(256) void mlp_up_kernel(
    const float* __restrict__ x, const float* __restrict__ w1, const float* __restrict__ b1,
    const float* __restrict__ w2, const float* __restrict__ b2, ushort* __restrict__ z){
  __shared__ float sw1[4*64];
  __shared__ float sw2[64*64];
  __shared__ float sb1[64], sb2[64];
  __shared__ float t1s[4][64];
  int tid = threadIdx.x;
  for (int i=tid;i<256;i+=256) sw1[i]=w1[i];
  for (int i=tid;i<4096;i+=256) sw2[i]=w2[i];
  if (tid<64){ sb1[tid]=b1[tid]; sb2[tid]=b2[tid]; }
  __syncthreads();
  int g = tid>>6;
  int c = tid&63;
  int node = blockIdx.x*4 + g;
  float acc = sb1[c];
  #pragma unroll
  for (int k=0;k<4;k++) acc += x[node*4+k]*sw1[k*64+c];
  t1s[g][c] = gelu_f(acc);
  __syncthreads();
  float acc2 = sb2[c];
  #pragma unroll 8
  for (int k=0;k<64;k++) acc2 += t1s[g][k]*sw2[k*64+c];
  z[(size_t)node*64+c] = f2b(acc2);
}

// ---------------- pos propagation (fp32, once) ----------------
template<int LDIN>
__global__ void posprop(const float* __restrict__ in, float* __restrict__ out,
                        const int* __restrict__ starts, const int* __restrict__ crow,
                        const float* __restrict__ cnrm){
  int v = blockIdx.x*256+threadIdx.x;
  if (v >= N_NODES) return;
  int s=starts[v], e=starts[v+1];
  float a0=0.f,a1=0.f,a2=0.f;
  for (int i=s;i<e;++i){
    int r=crow[i]; float nm=cnrm[i];
    a0 = fmaf(in[(size_t)r*LDIN+0], nm, a0);
    a1 = fmaf(in[(size_t)r*LDIN+1], nm, a1);
    a2 = fmaf(in[(size_t)r*LDIN+2], nm, a2);
  }
  float4 o = {a0,a1,a2,0.f};
  *(float4*)(out + (size_t)v*4) = o;
}

// posbias[n][c] = c1_b[c] + sum_k (A^k pos)[n] . W1p_k[:,c]   (bf16)
__global__ __launch_bounds__(256) void posbias_kernel(
    const float* __restrict__ pos, const float* __restrict__ P1,
    const float* __restrict__ P2, const float* __restrict__ P3,
    const float* __restrict__ c1w, const float* __restrict__ c1b,
    ushort* __restrict__ pb){
  __shared__ float sw[4][3][128];
  int tid=threadIdx.x;
  for (int i=tid; i<4*3*128; i+=256){
    int cc=i&127; int d=(i>>7)%3; int j=i/(3*128);
    sw[j][d][cc] = c1w[((size_t)j*67 + 64 + d)*128 + cc];
  }
  __syncthreads();
  int idx = blockIdx.x*256+tid;
  if (idx < N_NODES*128){
    int n = idx>>7, cc = idx&127;
    float a = c1b[cc];
    #pragma unroll
    for (int d=0;d<3;d++) a = fmaf(pos[(size_t)n*3+d], sw[0][d][cc], a);
    #pragma unroll
    for (int d=0;d<3;d++) a = fmaf(P1[(size_t)n*4+d], sw[1][d][cc], a);
    #pragma unroll
    for (int d=0;d<3;d++) a = fmaf(P2[(size_t)n*4+d], sw[2][d][cc], a);
    #pragma unroll
    for (int d=0;d<3;d++) a = fmaf(P3[(size_t)n*4+d], sw[3][d][cc], a);
    pb[idx]=f2b(a);
  }
}

// ---------------- prop 128ch: wave/node, 4 edges in flight, 16B loads ----------------
__global__ __launch_bounds__(256) void prop128(
    const ushort* __restrict__ h, ushort* __restrict__ out,
    const int* __restrict__ starts, const int* __restrict__ crow,
    const float* __restrict__ cnrm){
  int wv = threadIdx.x >> 6;
  int v = blockIdx.x*4 + wv;
  int t = threadIdx.x & 63;
  int g = t >> 4;          // edge slot 0..3
  int c = t & 15;          // channel slot (8 ch each)
  int s = starts[v], e = starts[v+1];
  float acc[8] = {0,0,0,0,0,0,0,0};
  for (int i=s; i<e; i+=64){
    int cnt = e - i; if (cnt > 64) cnt = 64;
    int r = 0; float nm = 0.f;
    if (t < cnt){ r = crow[i+t]; nm = cnrm[i+t]; }
    for (int jb=0; jb<cnt; jb+=4){
      int rr  = __shfl(r,  jb+g, 64);
      float w = __shfl(nm, jb+g, 64);
      uint4 hv = *(const uint4*)(h + (size_t)rr*128 + c*8);
      const uint* hp = (const uint*)&hv;
      #pragma unroll
      for (int q=0;q<4;q++){
        acc[2*q]   = fmaf(__uint_as_float(hp[q]<<16),          w, acc[2*q]);
        acc[2*q+1] = fmaf(__uint_as_float(hp[q]&0xffff0000u),  w, acc[2*q+1]);
      }
    }
  }
  #pragma unroll
  for (int q=0;q<8;q++){
    acc[q] += __shfl_xor(acc[q], 16, 64);
    acc[q] += __shfl_xor(acc[q], 32, 64);
  }
  if (g==0){
    uint4 o; uint* op=(uint*)&o;
    #pragma unroll
    for (int q=0;q<4;q++) op[q] = (uint)f2b(acc[2*q]) | ((uint)f2b(acc[2*q+1])<<16);
    *(uint4*)(out + (size_t)v*128 + c*8) = o;
  }
}

// ---------------- prop 64ch: 8 edges in flight ----------------
// MODE 0: plain write bf16; 1: +adj write bf16; 2: +adj+bias, logsoftmax -> bf16; 3: -> fp32
template<int MODE>
__global__ __launch_bounds__(256) void prop64(
    const ushort* __restrict__ h, void* __restrict__ outp,
    const ushort* __restrict__ adj, const float* __restrict__ bias,
    const int* __restrict__ starts, const int* __restrict__ crow,
    const float* __restrict__ cnrm){
  int wv = threadIdx.x >> 6;
  int v = blockIdx.x*4 + wv;
  int t = threadIdx.x & 63;
  int g = t >> 3;          // edge slot 0..7
  int c = t & 7;           // channel slot (8 ch each)
  int s = starts[v], e = starts[v+1];
  float acc[8] = {0,0,0,0,0,0,0,0};
  for (int i=s; i<e; i+=64){
    int cnt = e - i; if (cnt > 64) cnt = 64;
    int r = 0; float nm = 0.f;
    if (t < cnt){ r = crow[i+t]; nm = cnrm[i+t]; }
    for (int jb=0; jb<cnt; jb+=8){
      int rr  = __shfl(r,  jb+g, 64);
      float w = __shfl(nm, jb+g, 64);
      uint4 hv = *(const uint4*)(h + (size_t)rr*64 + c*8);
      const uint* hp = (const uint*)&hv;
      #pragma unroll
      for (int q=0;q<4;q++){
        acc[2*q]   = fmaf(__uint_as_float(hp[q]<<16),          w, acc[2*q]);
        acc[2*q+1] = fmaf(__uint_as_float(hp[q]&0xffff0000u),  w, acc[2*q+1]);
      }
    }
  }
  #pragma unroll
  for (int q=0;q<8;q++){
    acc[q] += __shfl_xor(acc[q], 8, 64);
    acc[q] += __shfl_xor(acc[q], 16, 64);
    acc[q] += __shfl_xor(acc[q], 32, 64);
  }
  if (MODE==0){
    if (g==0){
      uint4 o; uint* op=(uint*)&o;
      #pragma unroll
      for (int q=0;q<4;q++) op[q] = (uint)f2b(acc[2*q]) | ((uint)f2b(acc[2*q+1])<<16);
      *(uint4*)((ushort*)outp + (size_t)v*64 + c*8) = o;
    }
  } else if (MODE==1){
    if (g==0){
      uint4 av = *(const uint4*)(adj + (size_t)v*64 + c*8);
      const uint* ap=(const uint*)&av;
      uint4 o; uint* op=(uint*)&o;
      #pragma unroll
      for (int q=0;q<4;q++){
        float lo = acc[2*q]   + __uint_as_float(ap[q]<<16);
        float hi = acc[2*q+1] + __uint_as_float(ap[q]&0xffff0000u);
        op[q] = (uint)f2b(lo) | ((uint)f2b(hi)<<16);
      }
      *(uint4*)((ushort*)outp + (size_t)v*64 + c*8) = o;
    }
  } else {
    uint4 av = *(const uint4*)(adj + (size_t)v*64 + c*8);
    const uint* ap=(const uint*)&av;
    float vv[8];
    #pragma unroll
    for (int q=0;q<4;q++){
      vv[2*q]   = acc[2*q]   + __uint_as_float(ap[q]<<16)         + bias[c*8+2*q];
      vv[2*q+1] = acc[2*q+1] + __uint_as_float(ap[q]&0xffff0000u) + bias[c*8+2*q+1];
    }
    float m = vv[0];
    #pragma unroll
    for (int q=1;q<8;q++) m = fmaxf(m, vv[q]);
    m = fmaxf(m, __shfl_xor(m,1,64));
    m = fmaxf(m, __shfl_xor(m,2,64));
    m = fmaxf(m, __shfl_xor(m,4,64));
    float ssum = 0.f;
    #pragma unroll
    for (int q=0;q<8;q++) ssum += __expf(vv[q]-m);
    ssum += __shfl_xor(ssum,1,64);
    ssum += __shfl_xor(ssum,2,64);
    ssum += __shfl_xor(ssum,4,64);
    float lse = m + __logf(ssum);
    if (g==0){
      if (MODE==2){
        uint4 o; uint* op=(uint*)&o;
        #pragma unroll
        for (int q=0;q<4;q++) op[q] = (uint)f2b(vv[2*q]-lse) | ((uint)f2b(vv[2*q+1]-lse)<<16);
        *(uint4*)((ushort*)outp + (size_t)v*64 + c*8) = o;
      } else {
        float* zo = (float*)outp + (size_t)v*64 + c*8;
        #pragma unroll
        for (int q=0;q<8;q++) zo[q] = vv[q]-lse;
      }
    }
  }
}

// ---------------- MFMA gemm, 4 inputs (stride KC) -> 128 out, relu ----------------
template<int KC, bool PERNODE_BIAS>
__global__ __launch_bounds__(256) void gemm4in(
    const ushort* __restrict__ H0, const ushort* __restrict__ H1,
    const ushort* __restrict__ H2, const ushort* __restrict__ H3,
    const ushort* __restrict__ PB, const void* __restrict__ biasp,
    ushort* __restrict__ out){
  constexpr int NT = 8;
  constexpr int NKS = KC/32;
  int lane = threadIdx.x & 63;
  int wv   = threadIdx.x >> 6;
  int m0 = blockIdx.x*64 + wv*16;
  int lr = lane & 15, lg = lane >> 4;
  int arow = m0 + lr; if (arow > N_NODES-1) arow = N_NODES-1;
  const ushort* Hs[4] = {H0,H1,H2,H3};
  f32x4 acc[NT];
  #pragma unroll
  for (int t=0;t<NT;t++) acc[t] = (f32x4){0.f,0.f,0.f,0.f};
  #pragma unroll
  for (int j=0;j<4;j++){
    const ushort* Hj  = Hs[j] + (size_t)arow*KC + lg*8;
    const ushort* PBj = PB + (size_t)j*(KC/8)*128*8;
    #pragma unroll
    for (int ks=0; ks<NKS; ks++){
      bf16x8 af = *(const bf16x8*)(Hj + ks*32);
      int kb = ks*4 + lg;
      #pragma unroll
      for (int t=0;t<NT;t++){
        bf16x8 bf = *(const bf16x8*)(PBj + ((size_t)kb*128 + t*16 + lr)*8);
        acc[t] = __builtin_amdgcn_mfma_f32_16x16x32_bf16(af, bf, acc[t], 0, 0, 0);
      }
    }
  }
  #pragma unroll
  for (int t=0;t<NT;t++){
    #pragma unroll
    for (int q=0;q<4;q++){
      int node = m0 + lg*4 + q;
      if (node < N_NODES){
        int col = t*16 + lr;
        float b;
        if (PERNODE_BIAS) b = __uint_as_float(((uint)((const ushort*)biasp)[(size_t)node*128+col])<<16);
        else              b = ((const float*)biasp)[col];
        float vo = fmaxf(acc[t][q] + b, 0.f);
        out[(size_t)node*128 + col] = f2b(vo);
      }
    }
  }
}

// ---------------- MFMA gemm, 1 input (stride 128) -> 4x64 Y outputs ----------------
__global__ __launch_bounds__(256) void gemm_y(
    const ushort* __restrict__ T2, const ushort* __restrict__ PB,
    ushort* __restrict__ Y){
  constexpr int NT = 16;
  int lane = threadIdx.x & 63;
  int wv   = threadIdx.x >> 6;
  int m0 = blockIdx.x*64 + wv*16;
  int lr = lane & 15, lg = lane >> 4;
  int arow = m0 + lr; if (arow > N_NODES-1) arow = N_NODES-1;
  f32x4 acc[NT];
  #pragma unroll
  for (int t=0;t<NT;t++) acc[t] = (f32x4){0.f,0.f,0.f,0.f};
  const ushort* Hj = T2 + (size_t)arow*128 + lg*8;
  #pragma unroll
  for (int ks=0; ks<4; ks++){
    bf16x8 af = *(const bf16x8*)(Hj + ks*32);
    int kb = ks*4 + lg;
    #pragma unroll
    for (int t=0;t<NT;t++){
      bf16x8 bf = *(const bf16x8*)(PB + ((size_t)kb*256 + t*16 + lr)*8);
      acc[t] = __builtin_amdgcn_mfma_f32_16x16x32_bf16(af, bf, acc[t], 0, 0, 0);
    }
  }
  #pragma unroll
  for (int t=0;t<NT;t++){
    int n = t*16 + lr;
    int j = n >> 6, cc = n & 63;
    #pragma unroll
    for (int q=0;q<4;q++){
      int node = m0 + lg*4 + q;
      if (node < N_NODES)
        Y[(size_t)j*N_NODES*64 + (size_t)node*64 + cc] = f2b(acc[t][q]);
    }
  }
}

// ---------------- down MLP ----------------
__global__ __launch_bounds__(256) void mlp_down_kernel(
    const float* __restrict__ zs, const float* __restrict__ dw1, const float* __restrict__ db1,
    const float* __restrict__ dw2, const float* __restrict__ db2, float* __restrict__ out){
  int node = blockIdx.x*4 + (threadIdx.x>>6);
  int c = threadIdx.x & 63;
  float v = zs[(size_t)node*64+c]*dw1[c];
  #pragma unroll
  for (int off=32; off; off>>=1) v += __shfl_xor(v, off, 64);
  if (c==0) out[node] = gelu_f(v + db1[0]) * dw2[0] + db2[0];
}

extern "C" void kernel_launch(void* const* d_in, const int* in_sizes, int n_in,
                              void* d_out, int out_size, void* d_ws, size_t ws_size,
                              hipStream_t stream){
  const float* x     = (const float*)d_in[0];
  const float* pos   = (const float*)d_in[1];
  const float* eattr = (const float*)d_in[2];
  const float* up_w1 = (const float*)d_in[3];
  const float* up_b1 = (const float*)d_in[4];
  const float* up_w2 = (const float*)d_in[5];
  const float* up_b2 = (const float*)d_in[6];
  const float* c1_w  = (const float*)d_in[7];
  const float* c1_b  = (const float*)d_in[8];
  const float* c2_w  = (const float*)d_in[9];
  const float* c2_b  = (const float*)d_in[10];
  const float* c3_w  = (const float*)d_in[11];
  const float* c3_b  = (const float*)d_in[12];
  const float* dw1   = (const float*)d_in[13];
  const float* db1   = (const float*)d_in[14];
  const float* dw2   = (const float*)d_in[15];
  const float* db2   = (const float*)d_in[16];
  const int*   eidx  = (const int*)d_in[17];
  const int* row = eidx;
  const int* col = eidx + N_EDGES;

  char* wsp = (char*)d_ws;
  size_t off = 0;
  auto alloc = [&](size_t bytes)->char*{
    char* p = wsp + off;
    off = (off + bytes + 255) & ~(size_t)255;
    return p;
  };
  float*  deg    = (float*)alloc((size_t)N_NODES*4);
  int*    cnt    = (int*)  alloc((size_t)N_NODES*4);
  int*    starts = (int*)  alloc((size_t)(N_NODES+1)*4);
  int*    cursor = (int*)  alloc((size_t)N_NODES*4);
  float*  nrm    = (float*)alloc((size_t)N_EDGES*4);
  int*    crow   = (int*)  alloc((size_t)N_EDGES*4);
  float*  cnrm   = (float*)alloc((size_t)N_EDGES*4);
  float*  P1     = (float*)alloc((size_t)N_NODES*4*4);
  float*  P2     = (float*)alloc((size_t)N_NODES*4*4);
  float*  P3     = (float*)alloc((size_t)N_NODES*4*4);
  ushort* pbias  = (ushort*)alloc((size_t)N_NODES*128*2);
  ushort* z      = (ushort*)alloc((size_t)N_NODES*64*2);
  ushort* q1     = (ushort*)alloc((size_t)N_NODES*64*2);
  ushort* q2     = (ushort*)alloc((size_t)N_NODES*64*2);
  ushort* q3     = (ushort*)alloc((size_t)N_NODES*64*2);
  ushort* t1     = (ushort*)alloc((size_t)N_NODES*128*2);
  ushort* p1     = (ushort*)alloc((size_t)N_NODES*128*2);   // 12.8e6 B, 256-aligned exactly
  ushort* p2     = (ushort*)alloc((size_t)N_NODES*128*2);
  ushort* p3     = (ushort*)alloc((size_t)N_NODES*128*2);
  ushort* t2     = (ushort*)alloc((size_t)N_NODES*128*2);
  ushort* PB1    = (ushort*)alloc((size_t)4*8*128*8*2);
  ushort* PB2    = (ushort*)alloc((size_t)4*16*128*8*2);
  ushort* PB3    = (ushort*)alloc((size_t)16*256*8*2);

  // aliases: Y (4 x N*64 bf16 = 25.6MB) overlays p1+p2 (dead after gemm2);
  // u1,u2 reuse q1,q2 (dead after gemm1)
  ushort* Y  = p1;
  ushort* Y0 = Y;
  ushort* Y1 = Y + (size_t)1*N_NODES*64;
  ushort* Y2 = Y + (size_t)2*N_NODES*64;
  ushort* Y3 = Y + (size_t)3*N_NODES*64;
  ushort* u1 = q1;
  ushort* u2 = q2;

  float* outv  = (float*)d_out;            // (N,1)
  float* zstar = (float*)d_out + N_NODES;  // (N,64)

  hipMemsetAsync(deg, 0, (size_t)N_NODES*4, stream);
  hipMemsetAsync(cnt, 0, (size_t)N_NODES*4, stream);
  int eb = (N_EDGES+255)/256;
  deg_cnt_kernel<<<eb,256,0,stream>>>(col, eattr, deg, cnt);
  norm_kernel<<<eb,256,0,stream>>>(row, col, eattr, deg, nrm);
  scan_kernel<<<1,1024,0,stream>>>(cnt, starts, cursor);
  fill_kernel<<<eb,256,0,stream>>>(row, col, nrm, cursor, crow, cnrm);
  pack_w1<<<128,256,0,stream>>>(c1_w, PB1);
  pack_w2<<<256,256,0,stream>>>(c2_w, PB2);
  pack_w3<<<128,256,0,stream>>>(c3_w, PB3);
  mlp_up_kernel<<<N_NODES/4,256,0,stream>>>(x, up_w1, up_b1, up_w2, up_b2, z);

  // pos propagation chain + per-node layer-1 bias (once)
  int nb = (N_NODES+255)/256;
  posprop<3><<<nb,256,0,stream>>>(pos, P1, starts, crow, cnrm);
  posprop<4><<<nb,256,0,stream>>>(P1,  P2, starts, crow, cnrm);
  posprop<4><<<nb,256,0,stream>>>(P2,  P3, starts, crow, cnrm);
  posbias_kernel<<<(N_NODES*128)/256,256,0,stream>>>(pos, P1, P2, P3, c1_w, c1_b, pbias);

  const int gprop = N_NODES/4;             // 12500 blocks
  const int ggemm = (N_NODES+63)/64;       // 782 blocks

  for (int it=0; it<=MAX_ITER; ++it){
    // layer 1: propagate z (64ch), gemm K=64 with per-node posbias
    prop64<0><<<gprop,256,0,stream>>>(z,  q1, nullptr, nullptr, starts, crow, cnrm);
    prop64<0><<<gprop,256,0,stream>>>(q1, q2, nullptr, nullptr, starts, crow, cnrm);
    prop64<0><<<gprop,256,0,stream>>>(q2, q3, nullptr, nullptr, starts, crow, cnrm);
    gemm4in<64,true><<<ggemm,256,0,stream>>>(z,q1,q2,q3,PB1,pbias,t1);

    // layer 2: direct TAG at 128ch
    prop128<<<gprop,256,0,stream>>>(t1,p1,starts,crow,cnrm);
    prop128<<<gprop,256,0,stream>>>(p1,p2,starts,crow,cnrm);
    prop128<<<gprop,256,0,stream>>>(p2,p3,starts,crow,cnrm);
    gemm4in<128,false><<<ggemm,256,0,stream>>>(t1,p1,p2,p3,PB2,c2_b,t2);

    // layer 3: Horner — project first (128->4x64), then 64ch props
    gemm_y<<<ggemm,256,0,stream>>>(t2, PB3, Y);
    prop64<1><<<gprop,256,0,stream>>>(Y3, u1, Y2, nullptr, starts, crow, cnrm);
    prop64<1><<<gprop,256,0,stream>>>(u1, u2, Y1, nullptr, starts, crow, cnrm);
    if (it < MAX_ITER){
      prop64<2><<<gprop,256,0,stream>>>(u2, z, Y0, c3_b, starts, crow, cnrm);
    } else {
      prop64<3><<<gprop,256,0,stream>>>(u2, zstar, Y0, c3_b, starts, crow, cnrm);
    }
  }
  mlp_down_kernel<<<N_NODES/4,256,0,stream>>>(zstar, dw1, db1, dw2, db2, outv);
}